// Round 1
// 200.293 us; speedup vs baseline: 1.0589x; 1.0589x over previous
//
#include <hip/hip_runtime.h>

#define RADIUS 8
#define LR 256
#define HRES 1024
#define NC 24
#define GF_EPS 1e-4f
#define FSTRIP 8   // output rows per block: grid = NC * (256/8) = 768 blocks

typedef float f4 __attribute__((ext_vector_type(4)));  // native vector: nontemporal-builtin legal

// ---------------- Kernel F: fused LR stage (vertical running sums + horizontal 17-tap + algebra)
// One block per (img, 8-row strip), 256 threads = one per column.
// Vertical box window is a per-thread register running sum (add row y+8, sub row y-8,
// re-loaded from L2 -- whole image pair is 512 KB, always L2-resident).
// Horizontal 17-tap goes through a tiny 8 KB double-buffered LDS row of the 4 vertical sums.
// This replaces kH+kV: kills 25 MB of intermediate-plane stores + ~157 MB of amplified re-reads.
__global__ __launch_bounds__(256) void kF(const float* __restrict__ p,
                                          const float* __restrict__ I,
                                          float* __restrict__ A, float* __restrict__ B) {
    __shared__ float vI[2][LR], vp[2][LR], vIp[2][LR], vII[2][LR];
    const int x     = threadIdx.x;
    const int img   = blockIdx.x >> 5;       // / (LR/FSTRIP) = 32
    const int strip = blockIdx.x & 31;
    const int y0    = strip * FSTRIP;
    const int ib    = img * LR * LR;
    const float* Ii = I + ib;
    const float* pi = p + ib;

    // warm-up: vertical sums over rows [y0-8, y0+8] (truncated at edges)
    float sI = 0.f, sp_ = 0.f, sIp = 0.f, sII = 0.f;
    #pragma unroll 1
    for (int yy = y0 - RADIUS; yy <= y0 + RADIUS; ++yy) {
        if (yy >= 0 && yy < LR) {
            const float vi = Ii[yy * LR + x];
            const float vq = pi[yy * LR + x];
            sI  += vi;
            sp_ += vq;
            sIp += vi * vq;
            sII += vi * vi;
        }
    }
    const int cntx = min(x + RADIUS, LR - 1) - max(x - RADIUS, 0) + 1;

    // double-buffered LDS, single barrier per row (write buf[k&1]; sync; read buf[k&1];
    // buf[k&1] is only rewritten at k+2, which is after sync(k+1) -> safe).
    #pragma unroll 2
    for (int k = 0; k < FSTRIP; ++k) {
        const int y   = y0 + k;
        const int buf = k & 1;
        vI [buf][x] = sI;
        vp [buf][x] = sp_;
        vIp[buf][x] = sIp;
        vII[buf][x] = sII;
        __syncthreads();

        // issue next-row slide loads early so they overlap the LDS tap loop
        const int yadd = y + RADIUS + 1;
        const int ysub = y - RADIUS;
        float aI = 0.f, aq = 0.f, rI = 0.f, rq = 0.f;
        if (yadd < LR) { aI = Ii[yadd * LR + x]; aq = pi[yadd * LR + x]; }
        if (ysub >= 0) { rI = Ii[ysub * LR + x]; rq = pi[ysub * LR + x]; }

        // horizontal 17-tap over the staged vertical sums (stride-1 LDS: conflict-free)
        float hI = 0.f, hp = 0.f, hIp = 0.f, hII = 0.f;
        #pragma unroll
        for (int t = -RADIUS; t <= RADIUS; ++t) {
            const int   xt = x + t;
            const int   xx = min(max(xt, 0), LR - 1);
            const float m  = ((unsigned)xt < (unsigned)LR) ? 1.f : 0.f;  // truncated window
            hI  = fmaf(m, vI [buf][xx], hI);
            hp  = fmaf(m, vp [buf][xx], hp);
            hIp = fmaf(m, vIp[buf][xx], hIp);
            hII = fmaf(m, vII[buf][xx], hII);
        }

        const int   cnty = min(y + RADIUS, LR - 1) - max(y - RADIUS, 0) + 1;
        const float inv  = 1.0f / (float)(cntx * cnty);
        const float mI   = hI * inv;
        const float mp   = hp * inv;
        const float cov  = hIp * inv - mI * mp;
        const float var  = hII * inv - mI * mI;
        const float a    = cov / (var + GF_EPS);
        const float bb   = mp - a * mI;
        const int   idx  = ib + y * LR + x;
        A[idx] = a;
        B[idx] = bb;

        // slide the vertical window (zeros when out of range keep this branch-free)
        sI  += aI - rI;
        sp_ += aq - rq;
        sIp += fmaf(aI, aq, -rI * rq);
        sII += fmaf(aI, aI, -rI * rI);
    }
}

// ---------------- Kernel R: bilinear x4 upsample of A,B fused with A*I_hr + B -----
// One block per (img, PAIR of LR rows k,k+1) -> 8 HR rows. grid = NC*128.
// Stage the 8 vertically-lerped phase rows of A,B in LDS, then each thread issues
// ALL 8 float4 I_hr loads up-front (register array, nontemporal) before computing
// and storing -> 8 KB outstanding per wave, deep MLP.
// Phase table (HR row 8*k2+r, k=2*k2), rows clamped to [0,255]:
//   r=0: lerp(A[k-1],A[k],.625)   r=1: .875
//   r=2: lerp(A[k],A[k+1],.125)   r=3: .375
//   r=4: lerp(A[k],A[k+1],.625)   r=5: .875
//   r=6: lerp(A[k+1],A[k+2],.125) r=7: .375
__global__ __launch_bounds__(256) void kR(const float* __restrict__ A, const float* __restrict__ B,
                                          const float* __restrict__ Ihr, float* __restrict__ out) {
    __shared__ float av[8][LR];
    __shared__ float bv[8][LR];

    const int blk = blockIdx.x;
    const int img = blk >> 7;          // /128
    const int k2  = blk & 127;
    const int k   = k2 << 1;
    const int tx  = threadIdx.x;

    const float* Ai = A + img * LR * LR;
    const float* Bi = B + img * LR * LR;
    const int rm = max(k - 1, 0);
    const int rp = min(k + 2, LR - 1);

    const float aU = Ai[rm * LR + tx];        // row k-1 (clamped)
    const float a0 = Ai[k * LR + tx];         // row k
    const float a1 = Ai[(k + 1) * LR + tx];   // row k+1
    const float aD = Ai[rp * LR + tx];        // row k+2 (clamped)
    const float bU = Bi[rm * LR + tx];
    const float b0 = Bi[k * LR + tx];
    const float b1 = Bi[(k + 1) * LR + tx];
    const float bD = Bi[rp * LR + tx];

    av[0][tx] = aU + 0.625f * (a0 - aU);
    av[1][tx] = aU + 0.875f * (a0 - aU);
    av[2][tx] = a0 + 0.125f * (a1 - a0);
    av[3][tx] = a0 + 0.375f * (a1 - a0);
    av[4][tx] = a0 + 0.625f * (a1 - a0);
    av[5][tx] = a0 + 0.875f * (a1 - a0);
    av[6][tx] = a1 + 0.125f * (aD - a1);
    av[7][tx] = a1 + 0.375f * (aD - a1);
    bv[0][tx] = bU + 0.625f * (b0 - bU);
    bv[1][tx] = bU + 0.875f * (b0 - bU);
    bv[2][tx] = b0 + 0.125f * (b1 - b0);
    bv[3][tx] = b0 + 0.375f * (b1 - b0);
    bv[4][tx] = b0 + 0.625f * (b1 - b0);
    bv[5][tx] = b0 + 0.875f * (b1 - b0);
    bv[6][tx] = b1 + 0.125f * (bD - b1);
    bv[7][tx] = b1 + 0.375f * (bD - b1);
    __syncthreads();

    // HR row 4k has offset (4k)<<10 = k<<12 within the image.
    const long long base = ((long long)img << 20) + ((long long)k << 12) + (tx << 2);

    f4 ih[8];
    #pragma unroll
    for (int r = 0; r < 8; ++r)
        ih[r] = __builtin_nontemporal_load((const f4*)(Ihr + base + ((long long)r << 10)));

    const int cm1 = max(tx - 1, 0);
    const int cp1 = min(tx + 1, LR - 1);

    #pragma unroll
    for (int r = 0; r < 8; ++r) {
        const float am = av[r][cm1], ac = av[r][tx], ap = av[r][cp1];
        const float bm = bv[r][cm1], bc = bv[r][tx], bp = bv[r][cp1];
        float p0, p1, q0, q1;
        if (tx == 0) { p0 = ac; p1 = ac; q0 = bc; q1 = bc; }  // x<0 clamps to col 0
        else {
            p0 = am + 0.625f * (ac - am);
            p1 = am + 0.875f * (ac - am);
            q0 = bm + 0.625f * (bc - bm);
            q1 = bm + 0.875f * (bc - bm);
        }
        const float p2 = ac + 0.125f * (ap - ac);   // tx==255: ap==ac -> clamp ok
        const float p3 = ac + 0.375f * (ap - ac);
        const float q2 = bc + 0.125f * (bp - bc);
        const float q3 = bc + 0.375f * (bp - bc);

        f4 res;
        res.x = p0 * ih[r].x + q0;
        res.y = p1 * ih[r].y + q1;
        res.z = p2 * ih[r].z + q2;
        res.w = p3 * ih[r].w + q3;
        __builtin_nontemporal_store(res, (f4*)(out + base + ((long long)r << 10)));
    }
}

extern "C" void kernel_launch(void* const* d_in, const int* in_sizes, int n_in,
                              void* d_out, int out_size, void* d_ws, size_t ws_size,
                              hipStream_t stream) {
    const float* p_lr = (const float*)d_in[0];
    const float* I_lr = (const float*)d_in[1];
    const float* I_hr = (const float*)d_in[2];
    float* out = (float*)d_out;
    float* ws  = (float*)d_ws;

    const int S = NC * LR * LR;   // 1,572,864 floats per plane
    float* A = ws + 0 * (size_t)S;
    float* B = ws + 1 * (size_t)S;

    kF<<<NC * (LR / FSTRIP), 256, 0, stream>>>(p_lr, I_lr, A, B);
    kR<<<NC * 128, 256, 0, stream>>>(A, B, I_hr, out);
}